// Round 8
// baseline (349.707 us; speedup 1.0000x reference)
//
#include <hip/hip_runtime.h>
#include <hip/hip_bf16.h>
#include <stdint.h>

// Problem constants (from reference)
#define N_NODES 100000
#define N_EDGES 1600000
#define NFEAT   256
#define NHID    128
#define NEG_SLOPE 0.2f

#define NB_B       3125       // buckets of 32 nodes: 100000/32 exact
#define SLAB       1024       // fixed slab per bucket (mean fill 512)
#define BIN_BLOCKS 512        // 2 blocks/CU

typedef __attribute__((ext_vector_type(8))) short short8;   // 8 bf16 (4 VGPRs)
typedef __attribute__((ext_vector_type(4))) float f32x4;    // MFMA C/D frag

__device__ __forceinline__ int clamp_node(int v) {
    unsigned u = (unsigned)v;
    return (u < (unsigned)N_NODES) ? (int)u : 0;
}

// fp32 -> bf16 (RNE). Exact when the fp32 value is already bf16-rounded.
__device__ __forceinline__ unsigned short f2bf(float f) {
    unsigned u = __float_as_uint(f);
    return (unsigned short)((u + 0x7fffu + ((u >> 16) & 1u)) >> 16);
}
// packed pair -> v_cvt_pk_bf16_f32 (low = a, high = b)
__device__ __forceinline__ unsigned pkbf(float a, float b) {
    __hip_bfloat162 t = __float22bfloat162_rn(make_float2(a, b));
    return *reinterpret_cast<unsigned*>(&t);
}
__device__ __forceinline__ float bflo(unsigned p) { return __uint_as_float(p << 16); }
__device__ __forceinline__ float bfhi(unsigned p) { return __uint_as_float(p & 0xffff0000u); }

// ---------------------------------------------------------------------------
// K0: W [256,128] fp32 -> Wt [128,256] bf16 (n-major).
// ---------------------------------------------------------------------------
__global__ __launch_bounds__(256) void k_conv(
    const float* __restrict__ W, unsigned short* __restrict__ Wt)
{
    int id = blockIdx.x * 256 + threadIdx.x;  // n*256 + k
    int n = id >> 8, k = id & 255;
    Wt[id] = f2bf(W[k * NHID + n]);
}

// ---------------------------------------------------------------------------
// K1: h = x @ W via bf16 MFMA (fp32 accum). ROUND-1 STRUCTURE VERBATIM;
// only the epilogue changes: h is written as two half-column arrays
// hbA=[N][64] (cols 0-63) / hbB (cols 64-127). The wn wave split already
// partitions columns exactly this way -> zero extra cost.
// ---------------------------------------------------------------------------
#define LDS_STRIDE 40
__global__ __launch_bounds__(256) void k_gemm_mfma(
    const float* __restrict__ x,            // [N, 256] fp32
    const unsigned short* __restrict__ Wt,  // [128, 256] bf16, n-major
    const float* __restrict__ atts,         // [128]
    const float* __restrict__ attd,         // [128]
    unsigned short* __restrict__ hbA,       // [N, 64] bf16 cols 0-63
    unsigned short* __restrict__ hbB,       // [N, 64] bf16 cols 64-127
    float* __restrict__ asrc,
    float* __restrict__ adst)
{
    __shared__ unsigned short As[128 * LDS_STRIDE];
    __shared__ unsigned short Bs[128 * LDS_STRIDE];
    __shared__ float satt[128][2];

    const int tid  = threadIdx.x;
    const int wave = tid >> 6;
    const int lane = tid & 63;
    const int wm = wave >> 1, wn = wave & 1;
    const int lr = lane & 15, q = lane >> 4;
    const int blockM = blockIdx.x * 128;

    const int sr = tid >> 1;
    const int hh = tid & 1;

    if (tid < 128) { satt[tid][0] = 0.f; satt[tid][1] = 0.f; }

    f32x4 acc[4][4];
#pragma unroll
    for (int a = 0; a < 4; ++a)
#pragma unroll
        for (int b = 0; b < 4; ++b) acc[a][b] = 0.f;

    const int growA = min(blockM + sr, N_NODES - 1);
    const float* xrow = x + (size_t)growA * NFEAT + hh * 16;
    const unsigned short* wrow = Wt + sr * NFEAT + hh * 16;

    float4 va0, va1, va2, va3;
    uint4  vb0, vb1;
    {   // preload tile 0
        const float4* xp = (const float4*)xrow;
        va0 = xp[0]; va1 = xp[1]; va2 = xp[2]; va3 = xp[3];
        vb0 = *(const uint4*)(wrow);
        vb1 = *(const uint4*)(wrow + 8);
    }

    for (int kt = 0; kt < 8; ++kt) {
        __syncthreads();  // WAR: previous iter's frag reads done
        uint4 pa0 = make_uint4(pkbf(va0.x, va0.y), pkbf(va0.z, va0.w),
                               pkbf(va1.x, va1.y), pkbf(va1.z, va1.w));
        uint4 pa1 = make_uint4(pkbf(va2.x, va2.y), pkbf(va2.z, va2.w),
                               pkbf(va3.x, va3.y), pkbf(va3.z, va3.w));
        *(uint4*)&As[sr * LDS_STRIDE + hh * 16 + 0] = pa0;
        *(uint4*)&As[sr * LDS_STRIDE + hh * 16 + 8] = pa1;
        *(uint4*)&Bs[sr * LDS_STRIDE + hh * 16 + 0] = vb0;
        *(uint4*)&Bs[sr * LDS_STRIDE + hh * 16 + 8] = vb1;
        __syncthreads();  // RAW: writes visible

        if (kt < 7) {     // issue next tile's loads NOW (overlap MFMA)
            const float4* xp = (const float4*)(xrow + (kt + 1) * 32);
            va0 = xp[0]; va1 = xp[1]; va2 = xp[2]; va3 = xp[3];
            vb0 = *(const uint4*)(wrow + (kt + 1) * 32);
            vb1 = *(const uint4*)(wrow + (kt + 1) * 32 + 8);
        }

        short8 af[4], bfr[4];
#pragma unroll
        for (int mt = 0; mt < 4; ++mt)
            af[mt] = *(const short8*)&As[(wm * 64 + mt * 16 + lr) * LDS_STRIDE + q * 8];
#pragma unroll
        for (int nt = 0; nt < 4; ++nt)
            bfr[nt] = *(const short8*)&Bs[(wn * 64 + nt * 16 + lr) * LDS_STRIDE + q * 8];

#pragma unroll
        for (int mt = 0; mt < 4; ++mt)
#pragma unroll
            for (int nt = 0; nt < 4; ++nt)
                acc[mt][nt] = __builtin_amdgcn_mfma_f32_16x16x32_bf16(
                    af[mt], bfr[nt], acc[mt][nt], 0, 0, 0);
    }

    // ---- fused attention partials: per-row dot with atts/attd ----
    float attsv[4], attdv[4];
#pragma unroll
    for (int nt = 0; nt < 4; ++nt) {
        attsv[nt] = atts[wn * 64 + nt * 16 + lr];
        attdv[nt] = attd[wn * 64 + nt * 16 + lr];
    }
#pragma unroll
    for (int mt = 0; mt < 4; ++mt) {
#pragma unroll
        for (int reg = 0; reg < 4; ++reg) {
            float s = 0.f, d = 0.f;
#pragma unroll
            for (int nt = 0; nt < 4; ++nt) {
                float v = acc[mt][nt][reg];
                s += v * attsv[nt];
                d += v * attdv[nt];
            }
#pragma unroll
            for (int mask = 8; mask > 0; mask >>= 1) {
                s += __shfl_xor(s, mask);
                d += __shfl_xor(d, mask);
            }
            if (lr == 0) {
                int lrow = wm * 64 + mt * 16 + q * 4 + reg;
                atomicAdd(&satt[lrow][0], s);
                atomicAdd(&satt[lrow][1], d);
            }
        }
    }

    // ---- hb epilogue: split halves ----
    unsigned short* __restrict__ hbh = wn ? hbB : hbA;
#pragma unroll
    for (int mt = 0; mt < 4; ++mt) {
#pragma unroll
        for (int reg = 0; reg < 4; ++reg) {
            int grow = blockM + wm * 64 + mt * 16 + q * 4 + reg;
            if (grow < N_NODES) {
                unsigned short* hp = hbh + (size_t)grow * 64 + lr;
#pragma unroll
                for (int nt = 0; nt < 4; ++nt)
                    hp[nt * 16] = f2bf(acc[mt][nt][reg]);
            }
        }
    }

    __syncthreads();
    if (tid < 128) {
        int g = blockM + tid;
        if (g < N_NODES) {
            asrc[g] = satt[tid][0];
            adst[g] = satt[tid][1];
        }
    }
}

// ---------------------------------------------------------------------------
// K2: bin edges into fixed per-bucket slabs (bucket = dst>>5, slab = 1024).
// 32-node buckets (proven). Payload = src | (dst&31)<<17.
// ---------------------------------------------------------------------------
__global__ __launch_bounds__(256) void k_bin(
    const int* __restrict__ ei, int* __restrict__ gcur,
    unsigned* __restrict__ staged)
{
    __shared__ int hist[NB_B];   // then reused as cursor (12.5 KB)
    __shared__ int base[NB_B];   // 12.5 KB
    const int t = threadIdx.x;
    const int per = (N_EDGES + BIN_BLOCKS - 1) / BIN_BLOCKS;  // 3125
    const int e0 = blockIdx.x * per;
    const int e1 = min(e0 + per, N_EDGES);

    for (int i = t; i < NB_B; i += 256) hist[i] = 0;
    __syncthreads();
    for (int e = e0 + t; e < e1; e += 256)
        atomicAdd(&hist[clamp_node(ei[N_EDGES + e]) >> 5], 1);
    __syncthreads();
    for (int i = t; i < NB_B; i += 256) {
        int c = hist[i];
        base[i] = c ? atomicAdd(&gcur[i], c) : 0;
        hist[i] = 0;  // becomes cursor
    }
    __syncthreads();
    for (int e = e0 + t; e < e1; e += 256) {
        int d = clamp_node(ei[N_EDGES + e]);
        int s = clamp_node(ei[e]);
        int b = d >> 5;
        int pos = base[b] + atomicAdd(&hist[b], 1);
        if (pos < SLAB)  // Poisson(512) vs 1024: overflow prob ~0
            staged[(size_t)b * SLAB + pos] = (unsigned)s | ((unsigned)(d & 31) << 17);
    }
}

// ---------------------------------------------------------------------------
// K3a: half-column aggregation pass A (cols 0-63).
// Theory: sort_agg was pinned at ~71 us with FETCH invariant at 187 MB and
// "hbm" 2.7 TB/s across 3 very different code versions -> bound by L2-fill
// of the random hb gather (25.6 MB >> 4 MB/XCD L2). Splitting into two
// SEQUENTIAL half-column passes halves the live working set (12.8 MB) per
// pass -> per-XCD L2 coverage doubles. Pass A does the proven sort + half
// gather and persists sorted edges (bufG), per-node meta, ssum, and partial
// logits for pass B.
// ---------------------------------------------------------------------------
__global__ __launch_bounds__(256) void k_aggA(
    const unsigned* __restrict__ staged, const int* __restrict__ gcur,
    const float* __restrict__ asrc, const float* __restrict__ adst,
    const unsigned short* __restrict__ hbA,
    const float* __restrict__ bias, const float* __restrict__ fcw,
    float2* __restrict__ bufG, unsigned* __restrict__ metaG,
    float* __restrict__ ssumG, float2* __restrict__ l01)
{
    __shared__ float2 buf[SLAB];        // 8 KB sorted (src*32, ew)
    __shared__ int hist[32], scanv[32], cntv[32];
    __shared__ float asrc_s[32], adst_s[32];

    const int b = blockIdx.x;
    const int t = threadIdx.x;
    const int eb = b * SLAB;
    const int n = min(gcur[b], SLAB);
    const int nodeStart = b * 32;       // 3125*32 == 100000: no boundary

    if (t < 32) {
        hist[t] = 0;
        adst_s[t] = adst[nodeStart + t];
        asrc_s[t] = asrc[nodeStart + t];
    }
    __syncthreads();

    for (int j = t; j < n; j += 256)
        atomicAdd(&hist[(staged[eb + j] >> 17) & 31], 1);
    __syncthreads();

    if (t < 32) {  // parallel exclusive scan over 32 bins (lanes 0..31)
        int v = hist[t];
        int sc = v;
#pragma unroll
        for (int off = 1; off < 32; off <<= 1) {
            int u = __shfl_up(sc, off);
            if (t >= off) sc += u;
        }
        scanv[t] = sc - v;
        cntv[t] = v;
        hist[t] = 0;  // becomes cursor
        metaG[nodeStart + t] = (unsigned)(sc - v) | ((unsigned)v << 12);
    }
    __syncthreads();

    for (int j = t; j < n; j += 256) {
        unsigned pk = staged[eb + j];
        int s  = pk & 0x1FFFF;
        int dl = (pk >> 17) & 31;
        float a = asrc[s] + adst_s[dl];
        a = (a > 0.f) ? a : NEG_SLOPE * a;
        float ew = __expf(fminf(a, 60.f));
        int pos = scanv[dl] + atomicAdd(&hist[dl], 1);
        buf[pos] = make_float2(__int_as_float(s * 32), ew);  // uint-row base
    }
    __syncthreads();

    // persist sorted edges for pass B (coalesced)
    for (int j = t; j < n; j += 256) bufG[eb + j] = buf[j];

    // ---- aggregation (cols 0-63) + partial FC ----
    const int wave = t >> 6;
    const int lane = t & 63;
    const int l5 = lane & 31;
    const int eh = lane >> 5;
    const unsigned* hr = (const unsigned*)hbA;   // row i: hr[i*32 + l5]

    float b_[2], w0_[2], w1_[2];
#pragma unroll
    for (int k = 0; k < 2; ++k) {
        b_[k]  = bias[2 * l5 + k];          // global cols 2*l5, 2*l5+1 (< 64)
        w0_[k] = fcw[2 * l5 + k];
        w1_[k] = fcw[NHID + 2 * l5 + k];
    }

    for (int ln = wave * 8; ln < wave * 8 + 8; ++ln) {
        const int i = nodeStart + ln;
        const int jb = scanv[ln];
        const int nn = cntv[ln];

        float a0 = 0.f, a1 = 0.f;
        for (int j = 0; j < nn; j += 8) {
            float2 m[4]; unsigned p[4]; float ew[4];
#pragma unroll
            for (int u = 0; u < 4; ++u) {
                int e = j + 2 * u + eh;
                int idx = (e < nn) ? e : nn - 1;   // nn>=1 inside loop
                m[u] = buf[jb + idx];
                ew[u] = (e < nn) ? m[u].y : 0.f;
            }
#pragma unroll
            for (int u = 0; u < 4; ++u)
                p[u] = hr[__float_as_uint(m[u].x) + l5];
#pragma unroll
            for (int u = 0; u < 4; ++u) {
                a0 += ew[u] * bflo(p[u]);
                a1 += ew[u] * bfhi(p[u]);
            }
        }
        a0 += __shfl_xor(a0, 32);
        a1 += __shfl_xor(a1, 32);

        // ssum: lane-parallel over buf
        float ss = 0.f;
        for (int jj = lane; jj < nn; jj += 64) ss += buf[jb + jj].y;
#pragma unroll
        for (int off = 32; off > 0; off >>= 1) ss += __shfl_xor(ss, off);

        // self loop
        float e0 = asrc_s[ln] + adst_s[ln];
        e0 = (e0 > 0.f) ? e0 : NEG_SLOPE * e0;
        float w = __expf(fminf(e0, 60.f));
        unsigned pself = hr[(unsigned)i * 32u + l5];
        a0 += w * bflo(pself);
        a1 += w * bfhi(pself);
        ss += w;

        float inv = 1.0f / (ss + 1e-16f);
        float o0 = a0 * inv + b_[0];
        float o1 = a1 * inv + b_[1];

        float l0 = o0 * w0_[0] + o1 * w0_[1];
        float l1 = o0 * w1_[0] + o1 * w1_[1];
#pragma unroll
        for (int off = 16; off > 0; off >>= 1) {
            l0 += __shfl_down(l0, off);
            l1 += __shfl_down(l1, off);
        }
        if (lane == 0) {
            ssumG[i] = ss;
            l01[i] = make_float2(l0, l1);   // partial (no fcb)
        }
    }
}

// ---------------------------------------------------------------------------
// K3b: half-column aggregation pass B (cols 64-127). Sequential after A:
// skips sort/exp entirely (stages A's bufG), reads A's meta/ssum, adds A's
// partial logits + fcb, writes log_softmax.
// ---------------------------------------------------------------------------
__global__ __launch_bounds__(256) void k_aggB(
    const int* __restrict__ gcur,
    const float* __restrict__ asrc, const float* __restrict__ adst,
    const unsigned short* __restrict__ hbB,
    const float* __restrict__ bias, const float* __restrict__ fcw,
    const float* __restrict__ fcb,
    const float2* __restrict__ bufG, const unsigned* __restrict__ metaG,
    const float* __restrict__ ssumG, const float2* __restrict__ l01,
    float* __restrict__ out)
{
    __shared__ float2 buf[SLAB];        // 8 KB sorted (src*32, ew)
    __shared__ int scanv[32], cntv[32];
    __shared__ float asrc_s[32], adst_s[32], ssum_s[32];

    const int b = blockIdx.x;
    const int t = threadIdx.x;
    const int eb = b * SLAB;
    const int n = min(gcur[b], SLAB);
    const int nodeStart = b * 32;

    if (t < 32) {
        unsigned mv = metaG[nodeStart + t];
        scanv[t] = (int)(mv & 0xFFFu);
        cntv[t]  = (int)(mv >> 12);
        adst_s[t] = adst[nodeStart + t];
        asrc_s[t] = asrc[nodeStart + t];
        ssum_s[t] = ssumG[nodeStart + t];
    }
    for (int j = t; j < n; j += 256) buf[j] = bufG[eb + j];
    __syncthreads();

    const int wave = t >> 6;
    const int lane = t & 63;
    const int l5 = lane & 31;
    const int eh = lane >> 5;
    const unsigned* hr = (const unsigned*)hbB;   // row i: hr[i*32 + l5]

    float b_[2], w0_[2], w1_[2];
#pragma unroll
    for (int k = 0; k < 2; ++k) {
        b_[k]  = bias[64 + 2 * l5 + k];     // global cols 64 + 2*l5 + k
        w0_[k] = fcw[64 + 2 * l5 + k];
        w1_[k] = fcw[NHID + 64 + 2 * l5 + k];
    }
    const float fb0 = fcb[0], fb1 = fcb[1];

    for (int ln = wave * 8; ln < wave * 8 + 8; ++ln) {
        const int i = nodeStart + ln;
        const int jb = scanv[ln];
        const int nn = cntv[ln];

        float a0 = 0.f, a1 = 0.f;
        for (int j = 0; j < nn; j += 8) {
            float2 m[4]; unsigned p[4]; float ew[4];
#pragma unroll
            for (int u = 0; u < 4; ++u) {
                int e = j + 2 * u + eh;
                int idx = (e < nn) ? e : nn - 1;
                m[u] = buf[jb + idx];
                ew[u] = (e < nn) ? m[u].y : 0.f;
            }
#pragma unroll
            for (int u = 0; u < 4; ++u)
                p[u] = hr[__float_as_uint(m[u].x) + l5];
#pragma unroll
            for (int u = 0; u < 4; ++u) {
                a0 += ew[u] * bflo(p[u]);
                a1 += ew[u] * bfhi(p[u]);
            }
        }
        a0 += __shfl_xor(a0, 32);
        a1 += __shfl_xor(a1, 32);

        // self loop h-contribution (w recomputed; ssum already includes it)
        float e0 = asrc_s[ln] + adst_s[ln];
        e0 = (e0 > 0.f) ? e0 : NEG_SLOPE * e0;
        float w = __expf(fminf(e0, 60.f));
        unsigned pself = hr[(unsigned)i * 32u + l5];
        a0 += w * bflo(pself);
        a1 += w * bfhi(pself);
        float ss = ssum_s[ln];

        float inv = 1.0f / (ss + 1e-16f);
        float o0 = a0 * inv + b_[0];
        float o1 = a1 * inv + b_[1];

        float l0 = o0 * w0_[0] + o1 * w0_[1];
        float l1 = o0 * w1_[0] + o1 * w1_[1];
#pragma unroll
        for (int off = 16; off > 0; off >>= 1) {
            l0 += __shfl_down(l0, off);
            l1 += __shfl_down(l1, off);
        }
        if (lane == 0) {
            float2 part = l01[i];
            l0 += part.x + fb0;
            l1 += part.y + fb1;
            float m = fmaxf(l0, l1);
            float ls = m + __logf(__expf(l0 - m) + __expf(l1 - m));
            ((float2*)out)[i] = make_float2(l0 - ls, l1 - ls);
        }
    }
}

// ---------------------------------------------------------------------------
extern "C" void kernel_launch(void* const* d_in, const int* in_sizes, int n_in,
                              void* d_out, int out_size, void* d_ws, size_t ws_size,
                              hipStream_t stream)
{
    const float* x    = (const float*)d_in[0];
    const int*   ei   = (const int*)d_in[1];
    const float* W    = (const float*)d_in[2];
    const float* atts = (const float*)d_in[3];
    const float* attd = (const float*)d_in[4];
    const float* bias = (const float*)d_in[5];
    const float* fcw  = (const float*)d_in[6];
    const float* fcb  = (const float*)d_in[7];
    float*       out  = (float*)d_out;

    char* base = (char*)d_ws;
    size_t off = 0;
    auto carve = [&](size_t bytes) -> char* {
        char* p = base + off;
        off = (off + bytes + 255) & ~(size_t)255;
        return p;
    };
    unsigned short* hbA    = (unsigned short*)carve((size_t)N_NODES * 64 * 2);   // 12.8 MB
    unsigned short* hbB    = (unsigned short*)carve((size_t)N_NODES * 64 * 2);   // 12.8 MB
    float*          asrc   = (float*)carve(N_NODES * 4);
    float*          adst   = (float*)carve(N_NODES * 4);
    int*            gcur   = (int*)carve(NB_B * 4);
    unsigned*       staged = (unsigned*)carve((size_t)NB_B * SLAB * 4);          // 12.8 MB
    float2*         bufG   = (float2*)carve((size_t)NB_B * SLAB * 8);            // 25.6 MB
    unsigned*       metaG  = (unsigned*)carve(N_NODES * 4);
    float*          ssumG  = (float*)carve(N_NODES * 4);
    float2*         l01    = (float2*)carve(N_NODES * 8);
    unsigned short* Wt     = (unsigned short*)carve(NHID * NFEAT * 2);           // 64 KB
    (void)ws_size; (void)in_sizes; (void)n_in; (void)out_size;

    hipMemsetAsync(gcur, 0, NB_B * 4, stream);

    const int GB = (N_NODES + 127) / 128;  // 782

    k_conv<<<(NHID * NFEAT) / 256, 256, 0, stream>>>(W, Wt);
    k_gemm_mfma<<<GB, 256, 0, stream>>>(x, Wt, atts, attd, hbA, hbB, asrc, adst);
    k_bin<<<BIN_BLOCKS, 256, 0, stream>>>(ei, gcur, staged);
    k_aggA<<<NB_B, 256, 0, stream>>>(staged, gcur, asrc, adst, hbA,
                                     bias, fcw, bufG, metaG, ssumG, l01);
    k_aggB<<<NB_B, 256, 0, stream>>>(gcur, asrc, adst, hbB, bias, fcw, fcb,
                                     bufG, metaG, ssumG, l01, out);
}

// Round 9
// 316.394 us; speedup vs baseline: 1.1053x; 1.1053x over previous
//
#include <hip/hip_runtime.h>
#include <hip/hip_bf16.h>
#include <stdint.h>

// Problem constants (from reference)
#define N_NODES 100000
#define N_EDGES 1600000
#define NFEAT   256
#define NHID    128
#define NEG_SLOPE 0.2f

#define NB_B       3125       // buckets of 32 nodes: 100000/32 exact
#define SLAB       1024       // fixed slab per bucket (mean fill 512)
#define BIN_BLOCKS 128        // v2: was 512. Device-atomic contention on
#define BIN_THREADS 512       // gcur scales with block count (see k_bin).

typedef __attribute__((ext_vector_type(8))) short short8;   // 8 bf16 (4 VGPRs)
typedef __attribute__((ext_vector_type(4))) float f32x4;    // MFMA C/D frag

__device__ __forceinline__ int clamp_node(int v) {
    unsigned u = (unsigned)v;
    return (u < (unsigned)N_NODES) ? (int)u : 0;
}

// fp32 -> bf16 (RNE). Exact when the fp32 value is already bf16-rounded.
__device__ __forceinline__ unsigned short f2bf(float f) {
    unsigned u = __float_as_uint(f);
    return (unsigned short)((u + 0x7fffu + ((u >> 16) & 1u)) >> 16);
}
// packed pair -> v_cvt_pk_bf16_f32 (low = a, high = b)
__device__ __forceinline__ unsigned pkbf(float a, float b) {
    __hip_bfloat162 t = __float22bfloat162_rn(make_float2(a, b));
    return *reinterpret_cast<unsigned*>(&t);
}
__device__ __forceinline__ float bflo(unsigned p) { return __uint_as_float(p << 16); }
__device__ __forceinline__ float bfhi(unsigned p) { return __uint_as_float(p & 0xffff0000u); }

// ---------------------------------------------------------------------------
// K0: W [256,128] fp32 -> Wt [128,256] bf16 (n-major).
// ---------------------------------------------------------------------------
__global__ __launch_bounds__(256) void k_conv(
    const float* __restrict__ W, unsigned short* __restrict__ Wt)
{
    int id = blockIdx.x * 256 + threadIdx.x;  // n*256 + k
    int n = id >> 8, k = id & 255;
    Wt[id] = f2bf(W[k * NHID + n]);
}

// ---------------------------------------------------------------------------
// K1: h = x @ W via bf16 MFMA (fp32 accum) -> hb bf16 (unified [N][128],
// reverted from the R8 half-split). ROUND-1 STRUCTURE VERBATIM.
// Counters (R8): MfmaUtil 3.6%, VALUBusy 12%, occ 21% -> latency/grid-bound;
// candidate for BM=64 both-LDS next round.
// ---------------------------------------------------------------------------
#define LDS_STRIDE 40
__global__ __launch_bounds__(256) void k_gemm_mfma(
    const float* __restrict__ x,            // [N, 256] fp32 (bf16-valued)
    const unsigned short* __restrict__ Wt,  // [128, 256] bf16, n-major
    const float* __restrict__ atts,         // [128]
    const float* __restrict__ attd,         // [128]
    unsigned short* __restrict__ hb,        // [N, 128] bf16
    float* __restrict__ asrc,
    float* __restrict__ adst)
{
    __shared__ unsigned short As[128 * LDS_STRIDE];
    __shared__ unsigned short Bs[128 * LDS_STRIDE];
    __shared__ float satt[128][2];

    const int tid  = threadIdx.x;
    const int wave = tid >> 6;
    const int lane = tid & 63;
    const int wm = wave >> 1, wn = wave & 1;
    const int lr = lane & 15, q = lane >> 4;
    const int blockM = blockIdx.x * 128;

    const int sr = tid >> 1;
    const int hh = tid & 1;

    if (tid < 128) { satt[tid][0] = 0.f; satt[tid][1] = 0.f; }

    f32x4 acc[4][4];
#pragma unroll
    for (int a = 0; a < 4; ++a)
#pragma unroll
        for (int b = 0; b < 4; ++b) acc[a][b] = 0.f;

    const int growA = min(blockM + sr, N_NODES - 1);
    const float* xrow = x + (size_t)growA * NFEAT + hh * 16;
    const unsigned short* wrow = Wt + sr * NFEAT + hh * 16;

    float4 va0, va1, va2, va3;
    uint4  vb0, vb1;
    {   // preload tile 0
        const float4* xp = (const float4*)xrow;
        va0 = xp[0]; va1 = xp[1]; va2 = xp[2]; va3 = xp[3];
        vb0 = *(const uint4*)(wrow);
        vb1 = *(const uint4*)(wrow + 8);
    }

    for (int kt = 0; kt < 8; ++kt) {
        __syncthreads();  // WAR: previous iter's frag reads done
        uint4 pa0 = make_uint4(pkbf(va0.x, va0.y), pkbf(va0.z, va0.w),
                               pkbf(va1.x, va1.y), pkbf(va1.z, va1.w));
        uint4 pa1 = make_uint4(pkbf(va2.x, va2.y), pkbf(va2.z, va2.w),
                               pkbf(va3.x, va3.y), pkbf(va3.z, va3.w));
        *(uint4*)&As[sr * LDS_STRIDE + hh * 16 + 0] = pa0;
        *(uint4*)&As[sr * LDS_STRIDE + hh * 16 + 8] = pa1;
        *(uint4*)&Bs[sr * LDS_STRIDE + hh * 16 + 0] = vb0;
        *(uint4*)&Bs[sr * LDS_STRIDE + hh * 16 + 8] = vb1;
        __syncthreads();  // RAW: writes visible

        if (kt < 7) {     // issue next tile's loads NOW (overlap MFMA)
            const float4* xp = (const float4*)(xrow + (kt + 1) * 32);
            va0 = xp[0]; va1 = xp[1]; va2 = xp[2]; va3 = xp[3];
            vb0 = *(const uint4*)(wrow + (kt + 1) * 32);
            vb1 = *(const uint4*)(wrow + (kt + 1) * 32 + 8);
        }

        short8 af[4], bfr[4];
#pragma unroll
        for (int mt = 0; mt < 4; ++mt)
            af[mt] = *(const short8*)&As[(wm * 64 + mt * 16 + lr) * LDS_STRIDE + q * 8];
#pragma unroll
        for (int nt = 0; nt < 4; ++nt)
            bfr[nt] = *(const short8*)&Bs[(wn * 64 + nt * 16 + lr) * LDS_STRIDE + q * 8];

#pragma unroll
        for (int mt = 0; mt < 4; ++mt)
#pragma unroll
            for (int nt = 0; nt < 4; ++nt)
                acc[mt][nt] = __builtin_amdgcn_mfma_f32_16x16x32_bf16(
                    af[mt], bfr[nt], acc[mt][nt], 0, 0, 0);
    }

    // ---- fused attention partials: per-row dot with atts/attd ----
    float attsv[4], attdv[4];
#pragma unroll
    for (int nt = 0; nt < 4; ++nt) {
        attsv[nt] = atts[wn * 64 + nt * 16 + lr];
        attdv[nt] = attd[wn * 64 + nt * 16 + lr];
    }
#pragma unroll
    for (int mt = 0; mt < 4; ++mt) {
#pragma unroll
        for (int reg = 0; reg < 4; ++reg) {
            float s = 0.f, d = 0.f;
#pragma unroll
            for (int nt = 0; nt < 4; ++nt) {
                float v = acc[mt][nt][reg];
                s += v * attsv[nt];
                d += v * attdv[nt];
            }
#pragma unroll
            for (int mask = 8; mask > 0; mask >>= 1) {
                s += __shfl_xor(s, mask);
                d += __shfl_xor(d, mask);
            }
            if (lr == 0) {
                int lrow = wm * 64 + mt * 16 + q * 4 + reg;
                atomicAdd(&satt[lrow][0], s);
                atomicAdd(&satt[lrow][1], d);
            }
        }
    }

    // ---- hb epilogue ----
#pragma unroll
    for (int mt = 0; mt < 4; ++mt) {
#pragma unroll
        for (int reg = 0; reg < 4; ++reg) {
            int grow = blockM + wm * 64 + mt * 16 + q * 4 + reg;
            if (grow < N_NODES) {
                unsigned short* hp = hb + (size_t)grow * NHID + wn * 64 + lr;
#pragma unroll
                for (int nt = 0; nt < 4; ++nt)
                    hp[nt * 16] = f2bf(acc[mt][nt][reg]);
            }
        }
    }

    __syncthreads();
    if (tid < 128) {
        int g = blockM + tid;
        if (g < N_NODES) {
            asrc[g] = satt[tid][0];
            adst[g] = satt[tid][1];
        }
    }
}

// ---------------------------------------------------------------------------
// K2 v2: bin edges into per-bucket slabs. R8 counters exposed this kernel:
// 65.5 us at VALUBusy 2% / occ 17% -> ~98% idle, waiting on DEVICE-SCOPE
// atomicAdd returns. 512 blocks x 3125 shared gcur addresses = ~324
// colliding RMWs per address, serialized at the coherence point (~200 cy
// each, past the non-coherent per-XCD L2s) -> the per-address chain is the
// critical path. Fix: 128 blocks x 512 threads -> contention /4; streaming
// passes keep the same total thread count. Algorithm unchanged.
// ---------------------------------------------------------------------------
__global__ __launch_bounds__(BIN_THREADS) void k_bin(
    const int* __restrict__ ei, int* __restrict__ gcur,
    unsigned* __restrict__ staged)
{
    __shared__ int hist[NB_B];   // then reused as cursor (12.5 KB)
    __shared__ int base[NB_B];   // 12.5 KB
    const int t = threadIdx.x;
    const int per = (N_EDGES + BIN_BLOCKS - 1) / BIN_BLOCKS;  // 12500
    const int e0 = blockIdx.x * per;
    const int e1 = min(e0 + per, N_EDGES);

    for (int i = t; i < NB_B; i += BIN_THREADS) hist[i] = 0;
    __syncthreads();
    for (int e = e0 + t; e < e1; e += BIN_THREADS)
        atomicAdd(&hist[clamp_node(ei[N_EDGES + e]) >> 5], 1);
    __syncthreads();
    for (int i = t; i < NB_B; i += BIN_THREADS) {
        int c = hist[i];
        base[i] = c ? atomicAdd(&gcur[i], c) : 0;
        hist[i] = 0;  // becomes cursor
    }
    __syncthreads();
    for (int e = e0 + t; e < e1; e += BIN_THREADS) {
        int d = clamp_node(ei[N_EDGES + e]);
        int s = clamp_node(ei[e]);
        int b = d >> 5;
        int pos = base[b] + atomicAdd(&hist[b], 1);
        if (pos < SLAB)  // Poisson(512) vs 1024: overflow prob ~0
            staged[(size_t)b * SLAB + pos] = (unsigned)s | ((unsigned)(d & 31) << 17);
    }
}

// ---------------------------------------------------------------------------
// K3 v6 (REVERTED from R8 split -- the bufG round trip cost more than the
// L2-residency gain): counting sort in LDS, 2-edge-per-iteration gather
// (32 lanes x uint2), ssum out of the hot loop. Proven 71.4 us.
// ---------------------------------------------------------------------------
__global__ __launch_bounds__(256) void k_sort_agg(
    const unsigned* __restrict__ staged, const int* __restrict__ gcur,
    const float* __restrict__ asrc, const float* __restrict__ adst,
    const unsigned short* __restrict__ hb,
    const float* __restrict__ bias, const float* __restrict__ fcw,
    const float* __restrict__ fcb, float* __restrict__ out)
{
    __shared__ float2 buf[SLAB];        // 8 KB sorted (src*32, ew)
    __shared__ int hist[32], scanv[32], cntv[32];
    __shared__ float asrc_s[32], adst_s[32];

    const int b = blockIdx.x;
    const int t = threadIdx.x;
    const int eb = b * SLAB;
    const int n = min(gcur[b], SLAB);
    const int nodeStart = b * 32;       // 3125*32 == 100000: no boundary

    if (t < 32) {
        hist[t] = 0;
        adst_s[t] = adst[nodeStart + t];
        asrc_s[t] = asrc[nodeStart + t];
    }
    __syncthreads();

    for (int j = t; j < n; j += 256)
        atomicAdd(&hist[(staged[eb + j] >> 17) & 31], 1);
    __syncthreads();

    if (t < 32) {  // parallel exclusive scan over 32 bins (lanes 0..31)
        int v = hist[t];
        int sc = v;
#pragma unroll
        for (int off = 1; off < 32; off <<= 1) {
            int u = __shfl_up(sc, off);
            if (t >= off) sc += u;
        }
        scanv[t] = sc - v;
        cntv[t] = v;
        hist[t] = 0;  // becomes cursor
    }
    __syncthreads();

    for (int j = t; j < n; j += 256) {
        unsigned pk = staged[eb + j];
        int s  = pk & 0x1FFFF;
        int dl = (pk >> 17) & 31;
        float a = asrc[s] + adst_s[dl];
        a = (a > 0.f) ? a : NEG_SLOPE * a;
        float ew = __expf(fminf(a, 60.f));
        int pos = scanv[dl] + atomicAdd(&hist[dl], 1);
        buf[pos] = make_float2(__int_as_float(s * 32), ew);  // uint2-row base
    }
    __syncthreads();

    // ---- aggregation + fused FC + log_softmax ----
    const int wave = t >> 6;
    const int lane = t & 63;
    const int l5 = lane & 31;    // position within half-wave
    const int eh = lane >> 5;    // which edge of the pair
    const uint2* hr2 = (const uint2*)hb;   // row i: hr2[i*32 + l5]

    // per-lane FC constants: 4 consecutive cols 4*l5 .. 4*l5+3
    float b_[4], w0_[4], w1_[4];
#pragma unroll
    for (int k = 0; k < 4; ++k) {
        b_[k]  = bias[4 * l5 + k];
        w0_[k] = fcw[4 * l5 + k];
        w1_[k] = fcw[NHID + 4 * l5 + k];
    }
    const float fb0 = fcb[0], fb1 = fcb[1];

    for (int ln = wave * 8; ln < wave * 8 + 8; ++ln) {
        const int i = nodeStart + ln;
        const int jb = scanv[ln];
        const int nn = cntv[ln];

        float a0 = 0.f, a1 = 0.f, a2 = 0.f, a3 = 0.f;
        for (int j = 0; j < nn; j += 8) {
            float2 m[4]; uint2 p[4]; float ew[4];
#pragma unroll
            for (int u = 0; u < 4; ++u) {
                int e = j + 2 * u + eh;
                int idx = (e < nn) ? e : nn - 1;   // nn>=1 inside loop
                m[u] = buf[jb + idx];
                ew[u] = (e < nn) ? m[u].y : 0.f;
            }
#pragma unroll
            for (int u = 0; u < 4; ++u)
                p[u] = hr2[__float_as_uint(m[u].x) + l5];
#pragma unroll
            for (int u = 0; u < 4; ++u) {
                a0 += ew[u] * bflo(p[u].x);
                a1 += ew[u] * bfhi(p[u].x);
                a2 += ew[u] * bflo(p[u].y);
                a3 += ew[u] * bfhi(p[u].y);
            }
        }
        // merge even/odd-edge partials
        a0 += __shfl_xor(a0, 32);
        a1 += __shfl_xor(a1, 32);
        a2 += __shfl_xor(a2, 32);
        a3 += __shfl_xor(a3, 32);

        // ssum: lane-parallel over buf (out of the hot loop)
        float ss = 0.f;
        for (int jj = lane; jj < nn; jj += 64) ss += buf[jb + jj].y;
#pragma unroll
        for (int off = 32; off > 0; off >>= 1) ss += __shfl_xor(ss, off);

        // self loop (both half-waves load identical data -> dups stay valid)
        float e0 = asrc_s[ln] + adst_s[ln];
        e0 = (e0 > 0.f) ? e0 : NEG_SLOPE * e0;
        float w = __expf(fminf(e0, 60.f));
        uint2 pself = hr2[(unsigned)i * 32u + l5];
        a0 += w * bflo(pself.x);
        a1 += w * bfhi(pself.x);
        a2 += w * bflo(pself.y);
        a3 += w * bfhi(pself.y);
        ss += w;

        float inv = 1.0f / (ss + 1e-16f);
        float o0 = a0 * inv + b_[0];
        float o1 = a1 * inv + b_[1];
        float o2 = a2 * inv + b_[2];
        float o3 = a3 * inv + b_[3];

        float l0 = o0 * w0_[0] + o1 * w0_[1] + o2 * w0_[2] + o3 * w0_[3];
        float l1 = o0 * w1_[0] + o1 * w1_[1] + o2 * w1_[2] + o3 * w1_[3];
#pragma unroll
        for (int off = 16; off > 0; off >>= 1) {
            l0 += __shfl_down(l0, off);
            l1 += __shfl_down(l1, off);
        }
        if (lane == 0) {
            l0 += fb0;
            l1 += fb1;
            float m = fmaxf(l0, l1);
            float ls = m + __logf(__expf(l0 - m) + __expf(l1 - m));
            ((float2*)out)[i] = make_float2(l0 - ls, l1 - ls);
        }
    }
}

// ---------------------------------------------------------------------------
extern "C" void kernel_launch(void* const* d_in, const int* in_sizes, int n_in,
                              void* d_out, int out_size, void* d_ws, size_t ws_size,
                              hipStream_t stream)
{
    const float* x    = (const float*)d_in[0];
    const int*   ei   = (const int*)d_in[1];
    const float* W    = (const float*)d_in[2];
    const float* atts = (const float*)d_in[3];
    const float* attd = (const float*)d_in[4];
    const float* bias = (const float*)d_in[5];
    const float* fcw  = (const float*)d_in[6];
    const float* fcb  = (const float*)d_in[7];
    float*       out  = (float*)d_out;

    char* base = (char*)d_ws;
    size_t off = 0;
    auto carve = [&](size_t bytes) -> char* {
        char* p = base + off;
        off = (off + bytes + 255) & ~(size_t)255;
        return p;
    };
    unsigned short* hb     = (unsigned short*)carve((size_t)N_NODES * NHID * 2); // 25.6 MB
    float*          asrc   = (float*)carve(N_NODES * 4);
    float*          adst   = (float*)carve(N_NODES * 4);
    int*            gcur   = (int*)carve(NB_B * 4);
    unsigned*       staged = (unsigned*)carve((size_t)NB_B * SLAB * 4);          // 12.8 MB
    unsigned short* Wt     = (unsigned short*)carve(NHID * NFEAT * 2);           // 64 KB
    (void)ws_size; (void)in_sizes; (void)n_in; (void)out_size;

    hipMemsetAsync(gcur, 0, NB_B * 4, stream);

    const int GB = (N_NODES + 127) / 128;  // 782

    k_conv<<<(NHID * NFEAT) / 256, 256, 0, stream>>>(W, Wt);
    k_gemm_mfma<<<GB, 256, 0, stream>>>(x, Wt, atts, attd, hb, asrc, adst);
    k_bin<<<BIN_BLOCKS, BIN_THREADS, 0, stream>>>(ei, gcur, staged);
    k_sort_agg<<<NB_B, 256, 0, stream>>>(staged, gcur, asrc, adst, hb,
                                         bias, fcw, fcb, out);
}